// Round 1
// baseline (179.173 us; speedup 1.0000x reference)
//
#include <hip/hip_runtime.h>
#include <math.h>

#define B 2
#define C 256
#define H 128
#define W 128
#define H2 256
#define W2 256
#define CPT 8   // channels per thread in main kernel

// ---------------- Kernel 1: channel mean ----------------
// One block per (b,h) row. 256 threads = 8 channel-groups x 32 float4-columns.
__global__ void mean_kernel(const float* __restrict__ x, float* __restrict__ mean) {
    int bh = blockIdx.x;            // 0 .. B*H-1
    int b = bh / H, h = bh % H;
    int tid = threadIdx.x;
    int g  = tid >> 5;              // channel group 0..7
    int w4 = tid & 31;              // float4 column 0..31

    const float4* xb = (const float4*)x + (size_t)b * C * (H * W / 4)
                       + (size_t)h * (W / 4) + w4;
    const size_t cstride = H * W / 4;

    float4 acc = make_float4(0.f, 0.f, 0.f, 0.f);
    #pragma unroll 8
    for (int i = 0; i < C / 8; ++i) {
        float4 v = xb[(size_t)(g * (C / 8) + i) * cstride];
        acc.x += v.x; acc.y += v.y; acc.z += v.z; acc.w += v.w;
    }

    __shared__ float4 sm[256];
    sm[tid] = acc;
    __syncthreads();
    for (int s = 4; s >= 1; s >>= 1) {
        if (g < s) {
            float4 o = sm[tid + s * 32];
            acc.x += o.x; acc.y += o.y; acc.z += o.z; acc.w += o.w;
            sm[tid] = acc;
        }
        __syncthreads();
    }
    if (g == 0) {
        const float inv = 1.0f / C;
        float4 m = make_float4(acc.x * inv, acc.y * inv, acc.z * inv, acc.w * inv);
        ((float4*)mean)[(size_t)bh * (W / 4) + w4] = m;
    }
}

// ---------------- Kernel 2: softmax weights ----------------
// One thread per (b,y,x) upsampled pixel. Writes Kw[b][k][y][x].
__global__ void weights_kernel(const float* __restrict__ mean,
                               const float* __restrict__ Woff,
                               const float* __restrict__ boff,
                               float* __restrict__ Kw) {
    int idx = blockIdx.x * blockDim.x + threadIdx.x;
    if (idx >= B * H2 * W2) return;
    int x = idx % W2;
    int y = (idx / W2) % H2;
    int b = idx / (W2 * H2);
    const float* mb = mean + (size_t)b * H * W;

    // conv5x5 on nearest-up2(mean), zero padding 2
    float off0 = 0.f, off1 = 0.f;
    #pragma unroll
    for (int u = 0; u < 5; ++u) {
        int yy = y + u - 2;
        if (yy < 0 || yy >= H2) continue;
        int hh = yy >> 1;
        #pragma unroll
        for (int v = 0; v < 5; ++v) {
            int xx = x + v - 2;
            if (xx < 0 || xx >= W2) continue;
            float m = mb[hh * W + (xx >> 1)];
            off0 += m * Woff[u * 5 + v];
            off1 += m * Woff[25 + u * 5 + v];
        }
    }
    // shift = center + tanh(off+b)/4
    float s0 = tanhf(off0 + boff[0]) * 0.25f + ((x & 1) ? 0.25f : -0.25f);
    float s1 = tanhf(off1 + boff[1]) * 0.25f + ((y & 1) ? 0.25f : -0.25f);

    int h = y >> 1, w = x >> 1;
    float mc = mb[h * W + w];

    float lg[9];
    float mx = -1e30f;
    #pragma unroll
    for (int k = 0; k < 9; ++k) {
        int di = k / 3 - 1, dj = k % 3 - 1;
        int hh = h + di, ww = w + dj;
        float pm = (hh >= 0 && hh < H && ww >= 0 && ww < W) ? mb[hh * W + ww] : 0.f;
        float g = pm - mc;
        float grad = 1.0f / (g * g + 1.0f);
        float d0 = s0 - (float)dj;
        float d1 = s1 - (float)di;
        float kern = 1.0f / (d0 * d0 + d1 * d1 + 0.2f);
        float l = grad * kern;
        lg[k] = l;
        mx = fmaxf(mx, l);
    }
    float sum = 0.f;
    #pragma unroll
    for (int k = 0; k < 9; ++k) { lg[k] = expf(lg[k] - mx); sum += lg[k]; }
    float inv = 1.0f / sum;

    float* o = Kw + (size_t)b * 9 * (H2 * W2) + (size_t)y * W2 + x;
    #pragma unroll
    for (int k = 0; k < 9; ++k) o[(size_t)k * (H2 * W2)] = lg[k] * inv;
}

// ---------------- Kernel 3: CARAFE apply ----------------
// Thread = (b, channel-group, h, w). Holds 36 weights in regs, loops 8 channels.
__global__ void carafe_kernel(const float* __restrict__ x,
                              const float* __restrict__ Kw,
                              float* __restrict__ out) {
    int idx = blockIdx.x * blockDim.x + threadIdx.x;
    int w  = idx % W;
    int h  = (idx / W) % H;
    int cg = (idx / (W * H)) % (C / CPT);
    int b  = idx / (W * H * (C / CPT));

    int y0 = 2 * h, x0 = 2 * w;
    const float* kb = Kw + (size_t)b * 9 * (H2 * W2);

    float2 wk[2][9];
    #pragma unroll
    for (int k = 0; k < 9; ++k) {
        const float* kp = kb + (size_t)k * (H2 * W2) + (size_t)y0 * W2 + x0;
        wk[0][k] = *(const float2*)kp;
        wk[1][k] = *(const float2*)(kp + W2);
    }

    const float* xb = x   + (size_t)(b * C + cg * CPT) * (H * W);
    float*       ob = out + (size_t)(b * C + cg * CPT) * (H2 * W2);

    for (int cc = 0; cc < CPT; ++cc) {
        float p[9];
        #pragma unroll
        for (int k = 0; k < 9; ++k) {
            int hh = h + k / 3 - 1;
            int ww = w + k % 3 - 1;
            p[k] = (hh >= 0 && hh < H && ww >= 0 && ww < W) ? xb[hh * W + ww] : 0.f;
        }
        #pragma unroll
        for (int pp = 0; pp < 2; ++pp) {
            float2 acc = make_float2(0.f, 0.f);
            #pragma unroll
            for (int k = 0; k < 9; ++k) {
                acc.x += wk[pp][k].x * p[k];
                acc.y += wk[pp][k].y * p[k];
            }
            *(float2*)(ob + (size_t)(y0 + pp) * W2 + x0) = acc;
        }
        xb += H * W;
        ob += H2 * W2;
    }
}

extern "C" void kernel_launch(void* const* d_in, const int* in_sizes, int n_in,
                              void* d_out, int out_size, void* d_ws, size_t ws_size,
                              hipStream_t stream) {
    const float* x    = (const float*)d_in[0];
    const float* Woff = (const float*)d_in[1];
    const float* boff = (const float*)d_in[2];
    float* out = (float*)d_out;

    float* mean = (float*)d_ws;                 // B*H*W floats      (128 KiB)
    float* Kw   = mean + (size_t)B * H * W;     // B*9*H2*W2 floats  (4.5 MiB)

    mean_kernel<<<B * H, 256, 0, stream>>>(x, mean);

    int wt = B * H2 * W2;
    weights_kernel<<<(wt + 255) / 256, 256, 0, stream>>>(mean, Woff, boff, Kw);

    int mt = B * (C / CPT) * H * W;             // 1,048,576, divisible by 256
    carafe_kernel<<<mt / 256, 256, 0, stream>>>(x, Kw, out);
}

// Round 2
// 176.965 us; speedup vs baseline: 1.0125x; 1.0125x over previous
//
#include <hip/hip_runtime.h>
#include <math.h>

#define B 2
#define C 256
#define H 128
#define W 128
#define H2 256
#define W2 256
#define CPT 8   // channels per thread in main kernel
#define TW 16   // weights kernel tile width

// ---------------- Kernel 1: channel mean ----------------
// One block per (b,h) row. 1024 threads = 32 channel-groups x 32 float4-columns.
// 16 waves/CU with 8 independent float4 loads each -> latency well hidden.
__global__ __launch_bounds__(1024) void mean_kernel(const float* __restrict__ x,
                                                    float* __restrict__ mean) {
    int bh = blockIdx.x;            // 0 .. B*H-1
    int b = bh / H, h = bh % H;
    int tid = threadIdx.x;
    int g  = tid >> 5;              // channel group 0..31
    int w4 = tid & 31;              // float4 column 0..31

    const float4* xb = (const float4*)x + (size_t)b * C * (H * W / 4)
                       + (size_t)h * (W / 4) + w4;
    const size_t cstride = H * W / 4;

    float4 acc = make_float4(0.f, 0.f, 0.f, 0.f);
    #pragma unroll
    for (int i = 0; i < C / 32; ++i) {
        float4 v = xb[(size_t)(g * (C / 32) + i) * cstride];
        acc.x += v.x; acc.y += v.y; acc.z += v.z; acc.w += v.w;
    }

    __shared__ float4 sm[1024];
    sm[tid] = acc;
    __syncthreads();
    for (int s = 16; s >= 1; s >>= 1) {
        if (g < s) {
            float4 o = sm[tid + s * 32];
            acc.x += o.x; acc.y += o.y; acc.z += o.z; acc.w += o.w;
            sm[tid] = acc;
        }
        __syncthreads();
    }
    if (g == 0) {
        const float inv = 1.0f / C;
        float4 m = make_float4(acc.x * inv, acc.y * inv, acc.z * inv, acc.w * inv);
        ((float4*)mean)[(size_t)bh * (W / 4) + w4] = m;
    }
}

// ---------------- Kernel 2: softmax weights ----------------
// Block = 16x16 output pixels. Mean tile (10x10 + zero halo) and conv weights
// staged in LDS; all bounds checks disappear (halo holds zeros, and the >>1
// index algebra maps every conv/patch tap into the tile).
__global__ __launch_bounds__(256) void weights_kernel(const float* __restrict__ mean,
                                                      const float* __restrict__ Woff,
                                                      const float* __restrict__ boff,
                                                      float* __restrict__ Kw) {
    __shared__ float sm[10][12];
    __shared__ float sW[50];
    __shared__ float sb[2];

    int b  = blockIdx.z;
    int x0 = blockIdx.x * TW;
    int y0 = blockIdx.y * TW;
    int h0 = y0 >> 1, w0 = x0 >> 1;
    int tid = threadIdx.x;

    if (tid < 100) {
        int lh = tid / 10, lw = tid % 10;
        int hh = h0 - 1 + lh, ww = w0 - 1 + lw;
        sm[lh][lw] = (hh >= 0 && hh < H && ww >= 0 && ww < W)
                         ? mean[(size_t)b * H * W + hh * W + ww] : 0.f;
    }
    if (tid >= 128 && tid < 178) sW[tid - 128] = Woff[tid - 128];
    if (tid >= 192 && tid < 194) sb[tid - 192] = boff[tid - 192];
    __syncthreads();

    int tx = tid & 15, ty = tid >> 4;
    int y = y0 + ty, x = x0 + tx;

    // conv5x5 on nearest-up2(mean): all taps from LDS, no branches
    float off0 = 0.f, off1 = 0.f;
    #pragma unroll
    for (int u = 0; u < 5; ++u) {
        int lh = ((y + u - 2) >> 1) - (h0 - 1);
        #pragma unroll
        for (int v = 0; v < 5; ++v) {
            int lw = ((x + v - 2) >> 1) - (w0 - 1);
            float m = sm[lh][lw];
            off0 += m * sW[u * 5 + v];
            off1 += m * sW[25 + u * 5 + v];
        }
    }
    float s0 = tanhf(off0 + sb[0]) * 0.25f + ((x & 1) ? 0.25f : -0.25f);
    float s1 = tanhf(off1 + sb[1]) * 0.25f + ((y & 1) ? 0.25f : -0.25f);

    int lhc = (ty >> 1) + 1;       // center in tile coords
    int lwc = (tx >> 1) + 1;
    float mc = sm[lhc][lwc];

    float lg[9];
    float mx = -1e30f;
    #pragma unroll
    for (int k = 0; k < 9; ++k) {
        int di = k / 3 - 1, dj = k % 3 - 1;
        float pm = sm[lhc + di][lwc + dj];
        float g = pm - mc;
        float grad = 1.0f / (g * g + 1.0f);
        float d0 = s0 - (float)dj;
        float d1 = s1 - (float)di;
        float kern = 1.0f / (d0 * d0 + d1 * d1 + 0.2f);
        float l = grad * kern;
        lg[k] = l;
        mx = fmaxf(mx, l);
    }
    float sum = 0.f;
    #pragma unroll
    for (int k = 0; k < 9; ++k) { lg[k] = expf(lg[k] - mx); sum += lg[k]; }
    float inv = 1.0f / sum;

    float* o = Kw + (size_t)b * 9 * (H2 * W2) + (size_t)y * W2 + x;
    #pragma unroll
    for (int k = 0; k < 9; ++k) o[(size_t)k * (H2 * W2)] = lg[k] * inv;
}

// ---------------- Kernel 3: CARAFE apply ----------------
// Thread = (b, channel-group, h, w). Holds 36 weights in regs, loops 8 channels.
__global__ __launch_bounds__(256) void carafe_kernel(const float* __restrict__ x,
                                                     const float* __restrict__ Kw,
                                                     float* __restrict__ out) {
    int idx = blockIdx.x * blockDim.x + threadIdx.x;
    int w  = idx % W;
    int h  = (idx / W) % H;
    int cg = (idx / (W * H)) % (C / CPT);
    int b  = idx / (W * H * (C / CPT));

    int y0 = 2 * h, x0 = 2 * w;
    const float* kb = Kw + (size_t)b * 9 * (H2 * W2);

    float2 wk[2][9];
    #pragma unroll
    for (int k = 0; k < 9; ++k) {
        const float* kp = kb + (size_t)k * (H2 * W2) + (size_t)y0 * W2 + x0;
        wk[0][k] = *(const float2*)kp;
        wk[1][k] = *(const float2*)(kp + W2);
    }

    const float* xb = x   + (size_t)(b * C + cg * CPT) * (H * W);
    float*       ob = out + (size_t)(b * C + cg * CPT) * (H2 * W2);

    // hoist patch validity/offsets (wave-uniform except at row edges)
    int poff[9]; bool pval[9];
    #pragma unroll
    for (int k = 0; k < 9; ++k) {
        int di = k / 3 - 1, dj = k % 3 - 1;
        int hh = h + di, ww = w + dj;
        pval[k] = (hh >= 0) & (hh < H) & (ww >= 0) & (ww < W);
        poff[k] = hh * W + ww;
    }

    #pragma unroll 2
    for (int cc = 0; cc < CPT; ++cc) {
        float p[9];
        #pragma unroll
        for (int k = 0; k < 9; ++k)
            p[k] = pval[k] ? xb[poff[k]] : 0.f;
        #pragma unroll
        for (int pp = 0; pp < 2; ++pp) {
            float2 acc = make_float2(0.f, 0.f);
            #pragma unroll
            for (int k = 0; k < 9; ++k) {
                acc.x += wk[pp][k].x * p[k];
                acc.y += wk[pp][k].y * p[k];
            }
            *(float2*)(ob + (size_t)(y0 + pp) * W2 + x0) = acc;
        }
        xb += H * W;
        ob += H2 * W2;
    }
}

extern "C" void kernel_launch(void* const* d_in, const int* in_sizes, int n_in,
                              void* d_out, int out_size, void* d_ws, size_t ws_size,
                              hipStream_t stream) {
    const float* x    = (const float*)d_in[0];
    const float* Woff = (const float*)d_in[1];
    const float* boff = (const float*)d_in[2];
    float* out = (float*)d_out;

    float* mean = (float*)d_ws;                 // B*H*W floats      (128 KiB)
    float* Kw   = mean + (size_t)B * H * W;     // B*9*H2*W2 floats  (4.5 MiB)

    mean_kernel<<<B * H, 1024, 0, stream>>>(x, mean);

    dim3 wgrid(W2 / TW, H2 / TW, B);
    weights_kernel<<<wgrid, 256, 0, stream>>>(mean, Woff, boff, Kw);

    int mt = B * (C / CPT) * H * W;             // 1,048,576, divisible by 256
    carafe_kernel<<<mt / 256, 256, 0, stream>>>(x, Kw, out);
}

// Round 3
// 175.261 us; speedup vs baseline: 1.0223x; 1.0097x over previous
//
#include <hip/hip_runtime.h>
#include <math.h>

#define B 2
#define C 256
#define H 128
#define W 128
#define H2 256
#define W2 256
#define CPT 16  // channels per thread in main kernel
#define TW 16   // weights kernel tile width

// ---------------- Kernel 1: channel mean ----------------
// One block per (b,h) row. 1024 threads = 32 channel-groups x 32 float4-columns.
__global__ __launch_bounds__(1024) void mean_kernel(const float* __restrict__ x,
                                                    float* __restrict__ mean) {
    int bh = blockIdx.x;            // 0 .. B*H-1
    int b = bh / H, h = bh % H;
    int tid = threadIdx.x;
    int g  = tid >> 5;              // channel group 0..31
    int w4 = tid & 31;              // float4 column 0..31

    const float4* xb = (const float4*)x + (size_t)b * C * (H * W / 4)
                       + (size_t)h * (W / 4) + w4;
    const size_t cstride = H * W / 4;

    float4 acc = make_float4(0.f, 0.f, 0.f, 0.f);
    #pragma unroll
    for (int i = 0; i < C / 32; ++i) {
        float4 v = xb[(size_t)(g * (C / 32) + i) * cstride];
        acc.x += v.x; acc.y += v.y; acc.z += v.z; acc.w += v.w;
    }

    __shared__ float4 sm[1024];
    sm[tid] = acc;
    __syncthreads();
    for (int s = 16; s >= 1; s >>= 1) {
        if (g < s) {
            float4 o = sm[tid + s * 32];
            acc.x += o.x; acc.y += o.y; acc.z += o.z; acc.w += o.w;
            sm[tid] = acc;
        }
        __syncthreads();
    }
    if (g == 0) {
        const float inv = 1.0f / C;
        float4 m = make_float4(acc.x * inv, acc.y * inv, acc.z * inv, acc.w * inv);
        ((float4*)mean)[(size_t)bh * (W / 4) + w4] = m;
    }
}

// ---------------- Kernel 2: softmax weights ----------------
// Block = 16x16 output pixels. Mean tile (10x10 + zero halo) and conv weights
// staged in LDS; no bounds checks in the hot path.
__global__ __launch_bounds__(256) void weights_kernel(const float* __restrict__ mean,
                                                      const float* __restrict__ Woff,
                                                      const float* __restrict__ boff,
                                                      float* __restrict__ Kw) {
    __shared__ float sm[10][12];
    __shared__ float sW[50];
    __shared__ float sb[2];

    int b  = blockIdx.z;
    int x0 = blockIdx.x * TW;
    int y0 = blockIdx.y * TW;
    int h0 = y0 >> 1, w0 = x0 >> 1;
    int tid = threadIdx.x;

    if (tid < 100) {
        int lh = tid / 10, lw = tid % 10;
        int hh = h0 - 1 + lh, ww = w0 - 1 + lw;
        sm[lh][lw] = (hh >= 0 && hh < H && ww >= 0 && ww < W)
                         ? mean[(size_t)b * H * W + hh * W + ww] : 0.f;
    }
    if (tid >= 128 && tid < 178) sW[tid - 128] = Woff[tid - 128];
    if (tid >= 192 && tid < 194) sb[tid - 192] = boff[tid - 192];
    __syncthreads();

    int tx = tid & 15, ty = tid >> 4;
    int y = y0 + ty, x = x0 + tx;

    float off0 = 0.f, off1 = 0.f;
    #pragma unroll
    for (int u = 0; u < 5; ++u) {
        int lh = ((y + u - 2) >> 1) - (h0 - 1);
        #pragma unroll
        for (int v = 0; v < 5; ++v) {
            int lw = ((x + v - 2) >> 1) - (w0 - 1);
            float m = sm[lh][lw];
            off0 += m * sW[u * 5 + v];
            off1 += m * sW[25 + u * 5 + v];
        }
    }
    float s0 = tanhf(off0 + sb[0]) * 0.25f + ((x & 1) ? 0.25f : -0.25f);
    float s1 = tanhf(off1 + sb[1]) * 0.25f + ((y & 1) ? 0.25f : -0.25f);

    int lhc = (ty >> 1) + 1;
    int lwc = (tx >> 1) + 1;
    float mc = sm[lhc][lwc];

    float lg[9];
    float mx = -1e30f;
    #pragma unroll
    for (int k = 0; k < 9; ++k) {
        int di = k / 3 - 1, dj = k % 3 - 1;
        float pm = sm[lhc + di][lwc + dj];
        float g = pm - mc;
        float grad = 1.0f / (g * g + 1.0f);
        float d0 = s0 - (float)dj;
        float d1 = s1 - (float)di;
        float kern = 1.0f / (d0 * d0 + d1 * d1 + 0.2f);
        float l = grad * kern;
        lg[k] = l;
        mx = fmaxf(mx, l);
    }
    float sum = 0.f;
    #pragma unroll
    for (int k = 0; k < 9; ++k) { lg[k] = expf(lg[k] - mx); sum += lg[k]; }
    float inv = 1.0f / sum;

    float* o = Kw + (size_t)b * 9 * (H2 * W2) + (size_t)y * W2 + x;
    #pragma unroll
    for (int k = 0; k < 9; ++k) o[(size_t)k * (H2 * W2)] = lg[k] * inv;
}

// ---------------- Kernel 3: CARAFE apply ----------------
// Thread = (b, 16-channel group, h, w-pair). Two 2x2 output cells per thread:
// 18 float4 weights in regs (amortized over 16 channels), 12 x-loads/channel,
// 2 float4 stores/channel (1 KiB/wave, perfect coalescing).
__global__ __launch_bounds__(256) void carafe_kernel(const float* __restrict__ x,
                                                     const float* __restrict__ Kw,
                                                     float* __restrict__ out) {
    int idx = blockIdx.x * blockDim.x + threadIdx.x;
    int w2 = idx & 63;              // w-pair index; w = 2*w2
    int h  = (idx >> 6) & (H - 1);
    int cg = (idx >> 13) & (C / CPT - 1);
    int b  = idx >> 17;

    int w  = w2 * 2;
    int y0 = 2 * h, x0 = 2 * w;     // x0 divisible by 4 -> aligned float4

    // 18 float4 weights: rows y0,y0+1, cols x0..x0+3, for the 9 taps
    const float* kb = Kw + (size_t)b * 9 * (H2 * W2) + (size_t)y0 * W2 + x0;
    float4 wk[2][9];
    #pragma unroll
    for (int k = 0; k < 9; ++k) {
        wk[0][k] = *(const float4*)(kb + (size_t)k * (H2 * W2));
        wk[1][k] = *(const float4*)(kb + (size_t)k * (H2 * W2) + W2);
    }

    // 3x4 patch footprint: rows h-1..h+1, cols w-1..w+2
    int off[3][4]; bool val[3][4];
    #pragma unroll
    for (int r = 0; r < 3; ++r) {
        int hh = h - 1 + r;
        #pragma unroll
        for (int c = 0; c < 4; ++c) {
            int ww = w - 1 + c;
            val[r][c] = (hh >= 0) & (hh < H) & (ww >= 0) & (ww < W);
            off[r][c] = hh * W + ww;
        }
    }

    const float* xb = x   + (size_t)(b * C + cg * CPT) * (H * W);
    float*       ob = out + (size_t)(b * C + cg * CPT) * (H2 * W2)
                          + (size_t)y0 * W2 + x0;

    #pragma unroll 2
    for (int cc = 0; cc < CPT; ++cc) {
        float p[3][4];
        #pragma unroll
        for (int r = 0; r < 3; ++r)
            #pragma unroll
            for (int c = 0; c < 4; ++c)
                p[r][c] = val[r][c] ? xb[off[r][c]] : 0.f;

        #pragma unroll
        for (int pp = 0; pp < 2; ++pp) {
            float4 acc = make_float4(0.f, 0.f, 0.f, 0.f);
            #pragma unroll
            for (int k = 0; k < 9; ++k) {
                int ki = k / 3, kj = k % 3;
                float a  = p[ki][kj];       // pixel (h, w)   tap
                float bb = p[ki][kj + 1];   // pixel (h, w+1) tap
                acc.x += wk[pp][k].x * a;
                acc.y += wk[pp][k].y * a;
                acc.z += wk[pp][k].z * bb;
                acc.w += wk[pp][k].w * bb;
            }
            *(float4*)(ob + (size_t)pp * W2) = acc;
        }
        xb += H * W;
        ob += H2 * W2;
    }
}

extern "C" void kernel_launch(void* const* d_in, const int* in_sizes, int n_in,
                              void* d_out, int out_size, void* d_ws, size_t ws_size,
                              hipStream_t stream) {
    const float* x    = (const float*)d_in[0];
    const float* Woff = (const float*)d_in[1];
    const float* boff = (const float*)d_in[2];
    float* out = (float*)d_out;

    float* mean = (float*)d_ws;                 // B*H*W floats      (128 KiB)
    float* Kw   = mean + (size_t)B * H * W;     // B*9*H2*W2 floats  (4.5 MiB)

    mean_kernel<<<B * H, 1024, 0, stream>>>(x, mean);

    dim3 wgrid(W2 / TW, H2 / TW, B);
    weights_kernel<<<wgrid, 256, 0, stream>>>(mean, Woff, boff, Kw);

    int mt = B * (C / CPT) * H * (W / 2);       // 262,144 threads
    carafe_kernel<<<mt / 256, 256, 0, stream>>>(x, Kw, out);
}